// Round 5
// baseline (698.158 us; speedup 1.0000x reference)
//
#include <hip/hip_runtime.h>

#define NN 512
#define BATCH 256
#define T 8

typedef unsigned long long u64;
typedef unsigned u32;

// u64 max via f64 max: all keys are positive f64 bit patterns (< 2^62,
// exponent never all-ones) -> IEEE order == unsigned order. 1 instr/compare.
__device__ __forceinline__ u64 fm(u64 a, u64 b) {
    return (u64)__double_as_longlong(fmax(__longlong_as_double((long long)a),
                                          __longlong_as_double((long long)b)));
}

#define DPP_FMAX64(k, ctrl) do {                                              \
    int _lo = (int)(u32)(k); int _hi = (int)((k) >> 32);                      \
    int _olo = __builtin_amdgcn_update_dpp(_lo, _lo, ctrl, 0xf, 0xf, false);  \
    int _ohi = __builtin_amdgcn_update_dpp(_hi, _hi, ctrl, 0xf, 0xf, false);  \
    u64 _o = ((u64)(u32)_ohi << 32) | (u32)_olo;                              \
    (k) = fm((k), _o);                                                        \
} while (0)

#define WAVE_FMAX64(k) do {                                                   \
    DPP_FMAX64(k, 0x111); DPP_FMAX64(k, 0x112); DPP_FMAX64(k, 0x114);         \
    DPP_FMAX64(k, 0x118); DPP_FMAX64(k, 0x142); DPP_FMAX64(k, 0x143);         \
} while (0)

__device__ __forceinline__ u64 readlane64(u64 k, int l) {
    u32 lo = (u32)__builtin_amdgcn_readlane((int)(u32)k, l);
    u32 hi = (u32)__builtin_amdgcn_readlane((int)(k >> 32), l);
    return ((u64)hi << 32) | lo;
}

// 3-level register select of the alive word for column-word w (no memory)
__device__ __forceinline__ u64 amsel(int w, u64 a0, u64 a1, u64 a2, u64 a3,
                                     u64 a4, u64 a5, u64 a6, u64 a7) {
    u64 x01 = (w & 1) ? a1 : a0;
    u64 x23 = (w & 1) ? a3 : a2;
    u64 x45 = (w & 1) ? a5 : a4;
    u64 x67 = (w & 1) ? a7 : a6;
    u64 y0 = (w & 2) ? x23 : x01;
    u64 y1 = (w & 2) ? x67 : x45;
    return (w & 4) ? y1 : y0;
}

// ---------------------------------------------------------------------------
// Kernel 1: per-row top-T (desc value, asc col) -> first NN*T u64 of each
// batch's out region (staged to LDS by kernel 2 before outputs land there).
// Entry format: val_bits<<32 | col.
// ---------------------------------------------------------------------------
__global__ __launch_bounds__(256) void build_top(const float* __restrict__ s,
                                                 float* __restrict__ out) {
    const int wave = threadIdx.x >> 6;
    const int lane = threadIdx.x & 63;
    const int row_g = blockIdx.x * 4 + wave;
    const int b = row_g >> 9;
    const int r = row_g & (NN - 1);
    const float* rp = s + (size_t)row_g * NN;
    u64* dst = (u64*)(out + (size_t)b * NN * NN) + (size_t)r * T;

    const float4 a  = *(const float4*)(rp + 4 * lane);
    const float4 c2 = *(const float4*)(rp + 256 + 4 * lane);

    u64 kk0 = (((u64)__float_as_uint(a.x)  + 1) << 9) | (u32)(511 - (4*lane + 0));
    u64 kk1 = (((u64)__float_as_uint(a.y)  + 1) << 9) | (u32)(511 - (4*lane + 1));
    u64 kk2 = (((u64)__float_as_uint(a.z)  + 1) << 9) | (u32)(511 - (4*lane + 2));
    u64 kk3 = (((u64)__float_as_uint(a.w)  + 1) << 9) | (u32)(511 - (4*lane + 3));
    u64 kk4 = (((u64)__float_as_uint(c2.x) + 1) << 9) | (u32)(511 - (256 + 4*lane + 0));
    u64 kk5 = (((u64)__float_as_uint(c2.y) + 1) << 9) | (u32)(511 - (256 + 4*lane + 1));
    u64 kk6 = (((u64)__float_as_uint(c2.z) + 1) << 9) | (u32)(511 - (256 + 4*lane + 2));
    u64 kk7 = (((u64)__float_as_uint(c2.w) + 1) << 9) | (u32)(511 - (256 + 4*lane + 3));

    #pragma unroll
    for (int t = 0; t < T; ++t) {
        u64 m0 = fm(kk0, kk1), m1 = fm(kk2, kk3);
        u64 m2 = fm(kk4, kk5), m3 = fm(kk6, kk7);
        m0 = fm(m0, m1); m2 = fm(m2, m3);
        u64 bk = fm(m0, m2);
        WAVE_FMAX64(bk);
        bk = readlane64(bk, 63);

        const int wcol = 511 - (int)(bk & 511);
        const u32 vb = (u32)(bk >> 9) - 1u;
        if (lane == 0) dst[t] = ((u64)vb << 32) | (u32)wcol;

        const int owner = (wcol & 255) >> 2;
        const int slot  = ((wcol >> 8) << 2) | (wcol & 3);
        if (lane == owner) {
            kk0 = (slot == 0) ? 0 : kk0;  kk1 = (slot == 1) ? 0 : kk1;
            kk2 = (slot == 2) ? 0 : kk2;  kk3 = (slot == 3) ? 0 : kk3;
            kk4 = (slot == 4) ? 0 : kk4;  kk5 = (slot == 5) ? 0 : kk5;
            kk6 = (slot == 6) ? 0 : kk6;  kk7 = (slot == 7) ? 0 : kk7;
        }
    }
}

// ---------------------------------------------------------------------------
// Kernel 2: sequential greedy matching, one wave per batch element.
// Keys in registers:  key = (val_bits+1)<<32 | (512-row)<<16 | col, 0 = dead.
// Lane owns rows lane+64j (j=0..7); ptr fields packed 4b x 8 in one u32.
// Column-alive mask replicated in registers (am0..am7).
// Rescan: single generic block, all pending lanes walk their lists in
// parallel (2 entries per LDS round trip). Exhausted rows -> HBM rebuild.
// ---------------------------------------------------------------------------
__global__ __launch_bounds__(64) void greedy_match(const float* __restrict__ s,
                                                   float* __restrict__ out) {
    __shared__ __align__(16) u64 lst[NN][T];   // 32 KB

    const int b = blockIdx.x;
    const int lane = threadIdx.x;
    const float* sb = s + (size_t)b * NN * NN;
    float* ob = out + (size_t)b * NN * NN;

    // ---- stage candidate lists from out-region into LDS ----
    {
        const ulonglong2* src = (const ulonglong2*)ob;
        ulonglong2* dstl = (ulonglong2*)&lst[0][0];
        #pragma unroll
        for (int j = 0; j < 32; ++j)
            dstl[lane + 64 * j] = src[lane + 64 * j];
    }

    u64 am0 = ~0ull, am1 = ~0ull, am2 = ~0ull, am3 = ~0ull,
        am4 = ~0ull, am5 = ~0ull, am6 = ~0ull, am7 = ~0ull;

    u64 k0, k1, k2, k3, k4, k5, k6, k7;
    u32 ptrs = 0;
#define INITK(j, KJ) do {                                                     \
        const int r_ = lane + 64 * (j);                                       \
        const u64 e_ = lst[r_][0];                                            \
        KJ = (((e_ >> 32) + 1ull) << 32)                                      \
           | ((u64)(u32)(512 - r_) << 16) | (e_ & 511ull);                    \
    } while (0)
    INITK(0, k0); INITK(1, k1); INITK(2, k2); INITK(3, k3);
    INITK(4, k4); INITK(5, k5); INITK(6, k6); INITK(7, k7);
#undef INITK

    for (int step = 0; step < NN; ++step) {
        // ---- wave argmax over all 512 keys (13 f64max + 6 DPP levels) ----
        u64 m0 = fm(k0, k1), m1 = fm(k2, k3), m2 = fm(k4, k5), m3 = fm(k6, k7);
        m0 = fm(m0, m1); m2 = fm(m2, m3);
        u64 bk = fm(m0, m2);
        WAVE_FMAX64(bk);
        const u32 lo = (u32)__builtin_amdgcn_readlane((int)(u32)bk, 63);
        const int cstar = (int)(lo & 511u);
        const int rstar = 512 - (int)((lo >> 16) & 1023u);

        // ---- write output row rstar (fire-and-forget) ----
        float4 o0, o1;
        o0.x = (4 * lane + 0 == cstar) ? 1.0f : 0.0f;
        o0.y = (4 * lane + 1 == cstar) ? 1.0f : 0.0f;
        o0.z = (4 * lane + 2 == cstar) ? 1.0f : 0.0f;
        o0.w = (4 * lane + 3 == cstar) ? 1.0f : 0.0f;
        o1.x = (256 + 4 * lane + 0 == cstar) ? 1.0f : 0.0f;
        o1.y = (256 + 4 * lane + 1 == cstar) ? 1.0f : 0.0f;
        o1.z = (256 + 4 * lane + 2 == cstar) ? 1.0f : 0.0f;
        o1.w = (256 + 4 * lane + 3 == cstar) ? 1.0f : 0.0f;
        float* orow = ob + ((size_t)rstar << 9);
        *(float4*)(orow + 4 * lane) = o0;
        *(float4*)(orow + 256 + 4 * lane) = o1;

        // ---- kill col cstar (uniform selects on replicated masks) ----
        {
            const int cw = cstar >> 6;
            const u64 nb = ~(1ull << (cstar & 63));
            am0 = (cw == 0) ? (am0 & nb) : am0;  am1 = (cw == 1) ? (am1 & nb) : am1;
            am2 = (cw == 2) ? (am2 & nb) : am2;  am3 = (cw == 3) ? (am3 & nb) : am3;
            am4 = (cw == 4) ? (am4 & nb) : am4;  am5 = (cw == 5) ? (am5 & nb) : am5;
            am6 = (cw == 6) ? (am6 & nb) : am6;  am7 = (cw == 7) ? (am7 & nb) : am7;
        }

        // ---- kill row rstar (register, predicated) ----
        {
            const int rl = rstar & 63, rj = rstar >> 6;
            const bool mine = (lane == rl);
            k0 = (mine && rj == 0) ? 0ull : k0;  k1 = (mine && rj == 1) ? 0ull : k1;
            k2 = (mine && rj == 2) ? 0ull : k2;  k3 = (mine && rj == 3) ? 0ull : k3;
            k4 = (mine && rj == 4) ? 0ull : k4;  k5 = (mine && rj == 5) ? 0ull : k5;
            k6 = (mine && rj == 6) ? 0ull : k6;  k7 = (mine && rj == 7) ? 0ull : k7;
        }

        // ---- rescan: all pending lanes walk their lists concurrently ----
        u32 fb = 0;
        for (;;) {
            int sel = 8;   // first (lowest) j with head col == cstar, live
#define CONDJ(j, KJ) do {                                                     \
            const u32 t_ = (((u32)(KJ)) ^ (u32)cstar) & 511u;                 \
            const bool c_ = (t_ == 0u) && ((u32)((KJ) >> 32) != 0u);          \
            sel = c_ ? (j) : sel;                                             \
        } while (0)
            CONDJ(7, k7); CONDJ(6, k6); CONDJ(5, k5); CONDJ(4, k4);
            CONDJ(3, k3); CONDJ(2, k2); CONDJ(1, k1); CONDJ(0, k0);
#undef CONDJ
            if (__ballot(sel < 8) == 0) break;

            const int js  = (sel < 8) ? sel : 0;
            const int row = lane + 64 * js;
            const u64 rowfield = (u64)(u32)(512 - row) << 16;
            int p = (int)((ptrs >> (4 * js)) & 15u);
            u64 nk = 0;
            int newp = p;
            bool active = (sel < 8);
            while (__ballot(active)) {
                const int q0 = p + 1, q1 = p + 2;
                const u64 e0 = lst[row][(q0 > 7) ? 7 : q0];
                const u64 e1 = lst[row][(q1 > 7) ? 7 : q1];
                const int c0 = (int)(e0 & 511u), c1 = (int)(e1 & 511u);
                const u64 w0 = amsel(c0 >> 6, am0, am1, am2, am3, am4, am5, am6, am7);
                const u64 w1 = amsel(c1 >> 6, am0, am1, am2, am3, am4, am5, am6, am7);
                const bool a0 = active && (q0 <= 7) && (((w0 >> (c0 & 63)) & 1ull) != 0ull);
                const bool a1 = active && (q1 <= 7) && (((w1 >> (c1 & 63)) & 1ull) != 0ull);
                const bool found = a0 || a1;
                const bool exh = active && !found && (p >= 5);
                nk   = a0 ? (e0 + (1ull << 32) + rowfield) : nk;
                nk   = (!a0 && a1) ? (e1 + (1ull << 32) + rowfield) : nk;
                newp = a0 ? q0 : (a1 ? q1 : newp);
                fb  |= exh ? (1u << js) : 0u;
                active = active && !found && !exh;
                p += 2;
            }
            // predicated writeback (nk==0 for exhausted -> dead until rebuild)
            k0 = (sel == 0) ? nk : k0;  k1 = (sel == 1) ? nk : k1;
            k2 = (sel == 2) ? nk : k2;  k3 = (sel == 3) ? nk : k3;
            k4 = (sel == 4) ? nk : k4;  k5 = (sel == 5) ? nk : k5;
            k6 = (sel == 6) ? nk : k6;  k7 = (sel == 7) ? nk : k7;
            if (sel < 8)
                ptrs = (ptrs & ~(15u << (4 * js))) | ((u32)newp << (4 * js));
        }

        // ---- rare fallback: HBM reload of exhausted rows, top-1 rebuild ----
        if (__ballot(fb != 0u)) {
#define FBJ(j, KJ) do {                                                       \
    u64 mk_ = __ballot((fb >> (j)) & 1u);                                     \
    while (mk_) {                                                             \
        const int l_ = (int)__builtin_ctzll(mk_); mk_ &= mk_ - 1;             \
        const int r_ = l_ + 64 * (j);                                         \
        const float* rp_ = sb + (size_t)r_ * NN;                              \
        const float4 fa_ = *(const float4*)(rp_ + 4 * lane);                  \
        const float4 fv_ = *(const float4*)(rp_ + 256 + 4 * lane);            \
        const int sh_ = (4 * lane) & 63; const int w_ = lane >> 4;            \
        u64 xlo_ = (w_ == 0) ? am0 : (w_ == 1) ? am1 : (w_ == 2) ? am2 : am3; \
        u64 xhi_ = (w_ == 0) ? am4 : (w_ == 1) ? am5 : (w_ == 2) ? am6 : am7; \
        const u32 al8_ = ((u32)(xlo_ >> sh_) & 0xFu)                          \
                       | (((u32)(xhi_ >> sh_) & 0xFu) << 4);                  \
        u64 c0_ = (al8_ & 1u)   ? ((((u64)__float_as_uint(fa_.x) + 1) << 9) | (u32)(511 - (4*lane+0))) : 0; \
        u64 c1_ = (al8_ & 2u)   ? ((((u64)__float_as_uint(fa_.y) + 1) << 9) | (u32)(511 - (4*lane+1))) : 0; \
        u64 c2_ = (al8_ & 4u)   ? ((((u64)__float_as_uint(fa_.z) + 1) << 9) | (u32)(511 - (4*lane+2))) : 0; \
        u64 c3_ = (al8_ & 8u)   ? ((((u64)__float_as_uint(fa_.w) + 1) << 9) | (u32)(511 - (4*lane+3))) : 0; \
        u64 c4_ = (al8_ & 16u)  ? ((((u64)__float_as_uint(fv_.x) + 1) << 9) | (u32)(511 - (256+4*lane+0))) : 0; \
        u64 c5_ = (al8_ & 32u)  ? ((((u64)__float_as_uint(fv_.y) + 1) << 9) | (u32)(511 - (256+4*lane+1))) : 0; \
        u64 c6_ = (al8_ & 64u)  ? ((((u64)__float_as_uint(fv_.z) + 1) << 9) | (u32)(511 - (256+4*lane+2))) : 0; \
        u64 c7_ = (al8_ & 128u) ? ((((u64)__float_as_uint(fv_.w) + 1) << 9) | (u32)(511 - (256+4*lane+3))) : 0; \
        u64 n0_ = fm(c0_, c1_), n1_ = fm(c2_, c3_);                           \
        u64 n2_ = fm(c4_, c5_), n3_ = fm(c6_, c7_);                           \
        n0_ = fm(n0_, n1_); n2_ = fm(n2_, n3_);                               \
        u64 bw_ = fm(n0_, n2_);                                               \
        WAVE_FMAX64(bw_);                                                     \
        bw_ = readlane64(bw_, 63);                                            \
        const int wc_ = 511 - (int)(bw_ & 511);                               \
        const u32 hv_ = (u32)(bw_ >> 9);  /* val_bits+1 */                    \
        if (lane == l_) {                                                     \
            KJ = ((u64)hv_ << 32) | ((u64)(u32)(512 - r_) << 16) | (u32)wc_;  \
            ptrs |= (15u << (4 * (j)));                                       \
        }                                                                     \
    }                                                                         \
} while (0)
            FBJ(0, k0); FBJ(1, k1); FBJ(2, k2); FBJ(3, k3);
            FBJ(4, k4); FBJ(5, k5); FBJ(6, k6); FBJ(7, k7);
#undef FBJ
        }
    }
}

extern "C" void kernel_launch(void* const* d_in, const int* in_sizes, int n_in,
                              void* d_out, int out_size, void* d_ws, size_t ws_size,
                              hipStream_t stream) {
    const float* s = (const float*)d_in[0];
    float* out = (float*)d_out;

    build_top<<<dim3(BATCH * NN / 4), dim3(256), 0, stream>>>(s, out);
    greedy_match<<<dim3(BATCH), dim3(64), 0, stream>>>(s, out);
}

// Round 6
// 551.284 us; speedup vs baseline: 1.2664x; 1.2664x over previous
//
#include <hip/hip_runtime.h>

#define NN 512
#define BATCH 256
#define T 8

typedef unsigned long long u64;
typedef unsigned u32;

// u64 max via f64 max: all keys are positive f64 bit patterns (< 2^62,
// exponent never all-ones) -> IEEE order == unsigned order. 1 instr/compare.
__device__ __forceinline__ u64 fm(u64 a, u64 b) {
    return (u64)__double_as_longlong(fmax(__longlong_as_double((long long)a),
                                          __longlong_as_double((long long)b)));
}

#define DPP_FMAX64(k, ctrl) do {                                              \
    int _lo = (int)(u32)(k); int _hi = (int)((k) >> 32);                      \
    int _olo = __builtin_amdgcn_update_dpp(_lo, _lo, ctrl, 0xf, 0xf, false);  \
    int _ohi = __builtin_amdgcn_update_dpp(_hi, _hi, ctrl, 0xf, 0xf, false);  \
    u64 _o = ((u64)(u32)_ohi << 32) | (u32)_olo;                              \
    (k) = fm((k), _o);                                                        \
} while (0)

#define WAVE_FMAX64(k) do {                                                   \
    DPP_FMAX64(k, 0x111); DPP_FMAX64(k, 0x112); DPP_FMAX64(k, 0x114);         \
    DPP_FMAX64(k, 0x118); DPP_FMAX64(k, 0x142); DPP_FMAX64(k, 0x143);         \
} while (0)

__device__ __forceinline__ u64 readlane64(u64 k, int l) {
    u32 lo = (u32)__builtin_amdgcn_readlane((int)(u32)k, l);
    u32 hi = (u32)__builtin_amdgcn_readlane((int)(k >> 32), l);
    return ((u64)hi << 32) | lo;
}

// 3-level select of the alive word for column-word w
__device__ __forceinline__ u64 amsel(int w, u64 a0, u64 a1, u64 a2, u64 a3,
                                     u64 a4, u64 a5, u64 a6, u64 a7) {
    u64 x01 = (w & 1) ? a1 : a0;
    u64 x23 = (w & 1) ? a3 : a2;
    u64 x45 = (w & 1) ? a5 : a4;
    u64 x67 = (w & 1) ? a7 : a6;
    u64 y0 = (w & 2) ? x23 : x01;
    u64 y1 = (w & 2) ? x67 : x45;
    return (w & 4) ? y1 : y0;
}

// ---------------------------------------------------------------------------
// Kernel 1: per-row top-T (desc value, asc col) -> first NN*T u64 of each
// batch's out region (staged to LDS by kernel 2 before outputs land there).
// Entry format: val_bits<<32 | col.   (unchanged from round 5, proven)
// ---------------------------------------------------------------------------
__global__ __launch_bounds__(256) void build_top(const float* __restrict__ s,
                                                 float* __restrict__ out) {
    const int wave = threadIdx.x >> 6;
    const int lane = threadIdx.x & 63;
    const int row_g = blockIdx.x * 4 + wave;
    const int b = row_g >> 9;
    const int r = row_g & (NN - 1);
    const float* rp = s + (size_t)row_g * NN;
    u64* dst = (u64*)(out + (size_t)b * NN * NN) + (size_t)r * T;

    const float4 a  = *(const float4*)(rp + 4 * lane);
    const float4 c2 = *(const float4*)(rp + 256 + 4 * lane);

    u64 kk0 = (((u64)__float_as_uint(a.x)  + 1) << 9) | (u32)(511 - (4*lane + 0));
    u64 kk1 = (((u64)__float_as_uint(a.y)  + 1) << 9) | (u32)(511 - (4*lane + 1));
    u64 kk2 = (((u64)__float_as_uint(a.z)  + 1) << 9) | (u32)(511 - (4*lane + 2));
    u64 kk3 = (((u64)__float_as_uint(a.w)  + 1) << 9) | (u32)(511 - (4*lane + 3));
    u64 kk4 = (((u64)__float_as_uint(c2.x) + 1) << 9) | (u32)(511 - (256 + 4*lane + 0));
    u64 kk5 = (((u64)__float_as_uint(c2.y) + 1) << 9) | (u32)(511 - (256 + 4*lane + 1));
    u64 kk6 = (((u64)__float_as_uint(c2.z) + 1) << 9) | (u32)(511 - (256 + 4*lane + 2));
    u64 kk7 = (((u64)__float_as_uint(c2.w) + 1) << 9) | (u32)(511 - (256 + 4*lane + 3));

    #pragma unroll
    for (int t = 0; t < T; ++t) {
        u64 m0 = fm(kk0, kk1), m1 = fm(kk2, kk3);
        u64 m2 = fm(kk4, kk5), m3 = fm(kk6, kk7);
        m0 = fm(m0, m1); m2 = fm(m2, m3);
        u64 bk = fm(m0, m2);
        WAVE_FMAX64(bk);
        bk = readlane64(bk, 63);

        const int wcol = 511 - (int)(bk & 511);
        const u32 vb = (u32)(bk >> 9) - 1u;
        if (lane == 0) dst[t] = ((u64)vb << 32) | (u32)wcol;

        const int owner = (wcol & 255) >> 2;
        const int slot  = ((wcol >> 8) << 2) | (wcol & 3);
        if (lane == owner) {
            kk0 = (slot == 0) ? 0 : kk0;  kk1 = (slot == 1) ? 0 : kk1;
            kk2 = (slot == 2) ? 0 : kk2;  kk3 = (slot == 3) ? 0 : kk3;
            kk4 = (slot == 4) ? 0 : kk4;  kk5 = (slot == 5) ? 0 : kk5;
            kk6 = (slot == 6) ? 0 : kk6;  kk7 = (slot == 7) ? 0 : kk7;
        }
    }
}

// ---------------------------------------------------------------------------
// Kernel 2: lazy greedy matching, one wave per batch element.
// key = (val_bits+1)<<32 | (512-row)<<16 | col ; 0 = row dead.
// Heads may be STALE (col dead): pop -> scalar validity test -> if stale,
// cooperatively re-head that row from its sorted LDS list (lanes 0..7 read
// all 8 entries at once) or, if exhausted, HBM reload -> re-pop.
// Common path has ZERO ballots and no exec-mask blocks.
// ---------------------------------------------------------------------------
__global__ __launch_bounds__(64) void greedy_match(const float* __restrict__ s,
                                                   float* __restrict__ out) {
    __shared__ __align__(16) u64 lst[NN][T];   // 32 KB

    const int b = blockIdx.x;
    const int lane = threadIdx.x;
    const float* sb = s + (size_t)b * NN * NN;
    float* ob = out + (size_t)b * NN * NN;

    // ---- stage candidate lists from out-region into LDS ----
    {
        const ulonglong2* src = (const ulonglong2*)ob;
        ulonglong2* dstl = (ulonglong2*)&lst[0][0];
        #pragma unroll
        for (int j = 0; j < 32; ++j)
            dstl[lane + 64 * j] = src[lane + 64 * j];
    }

    u64 am0 = ~0ull, am1 = ~0ull, am2 = ~0ull, am3 = ~0ull,
        am4 = ~0ull, am5 = ~0ull, am6 = ~0ull, am7 = ~0ull;

    u64 k0, k1, k2, k3, k4, k5, k6, k7;
#define INITK(j, KJ) do {                                                     \
        const int r_ = lane + 64 * (j);                                       \
        const u64 e_ = lst[r_][0];                                            \
        KJ = (((e_ >> 32) + 1ull) << 32)                                      \
           | ((u64)(u32)(512 - r_) << 16) | (e_ & 511ull);                    \
    } while (0)
    INITK(0, k0); INITK(1, k1); INITK(2, k2); INITK(3, k3);
    INITK(4, k4); INITK(5, k5); INITK(6, k6); INITK(7, k7);
#undef INITK

    int done = 0;
    for (;;) {
        // ---- pop: argmax over all 512 keys ----
        u64 m0 = fm(k0, k1), m1 = fm(k2, k3), m2 = fm(k4, k5), m3 = fm(k6, k7);
        m0 = fm(m0, m1); m2 = fm(m2, m3);
        u64 bk = fm(m0, m2);
        WAVE_FMAX64(bk);
        const u32 lo = (u32)__builtin_amdgcn_readlane((int)(u32)bk, 63);
        const int cstar = (int)(lo & 511u);
        const int rstar = 512 - (int)((lo >> 16) & 1023u);
        const int cw = cstar >> 6;
        const u64 aw = amsel(cw, am0, am1, am2, am3, am4, am5, am6, am7);

        u64 nk;  // value written into (rstar owner lane, slot) at tail
        if ((aw >> (cstar & 63)) & 1ull) {
            // ================= ACCEPT (common path, no ballots) =============
            float4 o0, o1;
            o0.x = (4 * lane + 0 == cstar) ? 1.0f : 0.0f;
            o0.y = (4 * lane + 1 == cstar) ? 1.0f : 0.0f;
            o0.z = (4 * lane + 2 == cstar) ? 1.0f : 0.0f;
            o0.w = (4 * lane + 3 == cstar) ? 1.0f : 0.0f;
            o1.x = (256 + 4 * lane + 0 == cstar) ? 1.0f : 0.0f;
            o1.y = (256 + 4 * lane + 1 == cstar) ? 1.0f : 0.0f;
            o1.z = (256 + 4 * lane + 2 == cstar) ? 1.0f : 0.0f;
            o1.w = (256 + 4 * lane + 3 == cstar) ? 1.0f : 0.0f;
            float* orow = ob + ((size_t)rstar << 9);
            *(float4*)(orow + 4 * lane) = o0;
            *(float4*)(orow + 256 + 4 * lane) = o1;

            // kill col cstar (wave-uniform masks)
            const u64 nb = ~(1ull << (cstar & 63));
            am0 = (cw == 0) ? (am0 & nb) : am0;  am1 = (cw == 1) ? (am1 & nb) : am1;
            am2 = (cw == 2) ? (am2 & nb) : am2;  am3 = (cw == 3) ? (am3 & nb) : am3;
            am4 = (cw == 4) ? (am4 & nb) : am4;  am5 = (cw == 5) ? (am5 & nb) : am5;
            am6 = (cw == 6) ? (am6 & nb) : am6;  am7 = (cw == 7) ? (am7 & nb) : am7;

            nk = 0;  // kill row rstar
            ++done;
        } else {
            // ================= FIX stale row rstar ==========================
            const u64 e = lst[rstar][lane & 7];
            const int c = (int)(e & 511u);
            const u64 w = amsel(c >> 6, am0, am1, am2, am3, am4, am5, am6, am7);
            const bool al = ((w >> (c & 63)) & 1ull) != 0ull;
            const u64 mask = __ballot(al) & 0xFFull;
            const u64 rowf = (u64)(u32)(512 - rstar) << 16;
            if (mask) {
                const int idx = (int)__builtin_ctzll(mask);
                const u64 es = readlane64(e, idx);
                nk = (((es >> 32) + 1ull) << 32) | rowf | (es & 511ull);
            } else {
                // cold: cooperative HBM reload, top-1 among alive cols
                const float* rp = sb + (size_t)rstar * NN;
                const float4 fa = *(const float4*)(rp + 4 * lane);
                const float4 fv = *(const float4*)(rp + 256 + 4 * lane);
                const int sh = (4 * lane) & 63; const int wq = lane >> 4;
                u64 xlo = (wq == 0) ? am0 : (wq == 1) ? am1 : (wq == 2) ? am2 : am3;
                u64 xhi = (wq == 0) ? am4 : (wq == 1) ? am5 : (wq == 2) ? am6 : am7;
                const u32 al8 = ((u32)(xlo >> sh) & 0xFu)
                              | (((u32)(xhi >> sh) & 0xFu) << 4);
                u64 c0 = (al8 & 1u)   ? ((((u64)__float_as_uint(fa.x) + 1) << 9) | (u32)(511 - (4*lane+0))) : 0;
                u64 c1 = (al8 & 2u)   ? ((((u64)__float_as_uint(fa.y) + 1) << 9) | (u32)(511 - (4*lane+1))) : 0;
                u64 c2 = (al8 & 4u)   ? ((((u64)__float_as_uint(fa.z) + 1) << 9) | (u32)(511 - (4*lane+2))) : 0;
                u64 c3 = (al8 & 8u)   ? ((((u64)__float_as_uint(fa.w) + 1) << 9) | (u32)(511 - (4*lane+3))) : 0;
                u64 c4 = (al8 & 16u)  ? ((((u64)__float_as_uint(fv.x) + 1) << 9) | (u32)(511 - (256+4*lane+0))) : 0;
                u64 c5 = (al8 & 32u)  ? ((((u64)__float_as_uint(fv.y) + 1) << 9) | (u32)(511 - (256+4*lane+1))) : 0;
                u64 c6 = (al8 & 64u)  ? ((((u64)__float_as_uint(fv.z) + 1) << 9) | (u32)(511 - (256+4*lane+2))) : 0;
                u64 c7 = (al8 & 128u) ? ((((u64)__float_as_uint(fv.w) + 1) << 9) | (u32)(511 - (256+4*lane+3))) : 0;
                u64 n0 = fm(c0, c1), n1 = fm(c2, c3);
                u64 n2 = fm(c4, c5), n3 = fm(c6, c7);
                n0 = fm(n0, n1); n2 = fm(n2, n3);
                u64 bw = fm(n0, n2);
                WAVE_FMAX64(bw);
                bw = readlane64(bw, 63);
                const int wc = 511 - (int)(bw & 511);
                nk = ((bw >> 9) << 32) | rowf | (u32)wc;   // (val+1)<<32 |...
            }
        }

        // ---- shared tail: write nk into rstar's owner lane/slot ----
        {
            const int rl = rstar & 63, rj = rstar >> 6;
            const bool mine = (lane == rl);
            k0 = (mine && rj == 0) ? nk : k0;  k1 = (mine && rj == 1) ? nk : k1;
            k2 = (mine && rj == 2) ? nk : k2;  k3 = (mine && rj == 3) ? nk : k3;
            k4 = (mine && rj == 4) ? nk : k4;  k5 = (mine && rj == 5) ? nk : k5;
            k6 = (mine && rj == 6) ? nk : k6;  k7 = (mine && rj == 7) ? nk : k7;
        }
        if (done == NN) break;
    }
}

extern "C" void kernel_launch(void* const* d_in, const int* in_sizes, int n_in,
                              void* d_out, int out_size, void* d_ws, size_t ws_size,
                              hipStream_t stream) {
    const float* s = (const float*)d_in[0];
    float* out = (float*)d_out;

    build_top<<<dim3(BATCH * NN / 4), dim3(256), 0, stream>>>(s, out);
    greedy_match<<<dim3(BATCH), dim3(64), 0, stream>>>(s, out);
}